// Round 9
// baseline (236.418 us; speedup 1.0000x reference)
//
#include <hip/hip_runtime.h>
#include <hip/hip_bf16.h>

typedef __attribute__((ext_vector_type(8))) short short8;
typedef __attribute__((ext_vector_type(4))) short short4v;
typedef __attribute__((ext_vector_type(4))) float f32x4;
typedef __attribute__((ext_vector_type(2))) float f32x2;

__device__ __forceinline__ unsigned short f2bf(float f) {
    unsigned int u = __builtin_bit_cast(unsigned int, f);
    u += 0x7fffu + ((u >> 16) & 1u);   // round-to-nearest-even
    return (unsigned short)(u >> 16);
}
__device__ __forceinline__ short4v cvt4(float a, float b, float c, float d) {
    union { __hip_bfloat162 h[2]; short4v s; } u;
    u.h[0] = __float22bfloat162_rn(make_float2(a, b));
    u.h[1] = __float22bfloat162_rn(make_float2(c, d));
    return u.s;
}

// ---------------------------------------------------------------------------
// Kernel A: partial adjacency sums over 60-frame chunks. grid (5,32).
// ---------------------------------------------------------------------------
__global__ void kA(const float* __restrict__ xx, float* __restrict__ At_part) {
    __shared__ float xs3[3][60][25];
    const int tc = blockIdx.x, n = blockIdx.y;
    const int tid = threadIdx.x;
    const float* base = xx + (size_t)n * 22500 + tc * 1500;
    for (int idx = tid; idx < 4500; idx += 256) {
        int ch = idx / 1500, rt = idx % 1500;
        xs3[ch][rt / 25][rt % 25] = base[ch * 7500 + rt];
    }
    __syncthreads();
    for (int p = tid; p < 625; p += 256) {
        int v = p / 25, u = p % 25;
        float s = 0.f;
        for (int t = 0; t < 60; ++t) {
            float dx = xs3[0][t][v] - xs3[0][t][u];
            float dy = xs3[1][t][v] - xs3[1][t][u];
            float dz = xs3[2][t][v] - xs3[2][t][u];
            s += __expf(-2.f * (dx * dx + dy * dy + dz * dz));
        }
        At_part[(size_t)(n * 5 + tc) * 625 + p] = s;
    }
}

// ---------------------------------------------------------------------------
// Kernel B1: per-sample reduce + symmetric normalization. grid 32.
// ---------------------------------------------------------------------------
__global__ void kB1(const float* __restrict__ At_part, float* __restrict__ Acontrib) {
    __shared__ float At[625];
    __shared__ float dinv[25];
    const int n = blockIdx.x, tid = threadIdx.x;
    for (int p = tid; p < 625; p += 256) {
        float s = 0.f;
        for (int tc = 0; tc < 5; ++tc) s += At_part[(size_t)(n * 5 + tc) * 625 + p];
        At[p] = s;
    }
    __syncthreads();
    if (tid < 25) {
        float d = 0.f;
        for (int u = 0; u < 25; ++u) d += At[tid * 25 + u];
        dinv[tid] = rsqrtf(d * (1.f / 300.f));
    }
    __syncthreads();
    for (int p = tid; p < 625; p += 256)
        Acontrib[n * 625 + p] = At[p] * (1.f / 300.f) * dinv[p / 25] * dinv[p % 25] * (1.f / 32.f);
}

// ---------------------------------------------------------------------------
// Kernel B2: block 0 -> bsTg (bf16 [64][72], zero-padded) + fused bias;
//            blocks 1..36 -> W'' = W * bn_scale  (layout [o][k], row-major).
// ---------------------------------------------------------------------------
__global__ void kB2(const float* __restrict__ Acontrib, const float* __restrict__ A_res,
                    const float* __restrict__ W, const float* __restrict__ b,
                    const float* __restrict__ gamma, const float* __restrict__ beta,
                    const float* __restrict__ rm, const float* __restrict__ rv,
                    short* __restrict__ bsTg, short* __restrict__ Wpg,
                    float* __restrict__ bbg) {
    const int tid = threadIdx.x;
    if (blockIdx.x == 0) {
        __shared__ float macc[625];
        for (int p = tid; p < 625; p += 256) {
            float s = 0.f;
            for (int n = 0; n < 32; ++n) s += Acontrib[n * 625 + p];
            macc[p] = s;
        }
        __syncthreads();
        for (int idx = tid; idx < 64 * 72; idx += 256) {
            int col = idx / 72, u = idx % 72;
            float v = 0.f;
            if (col < 50 && u < 50) v = macc[(col % 25) * 25 + (u % 25)] + A_res[col * 50 + u];
            bsTg[idx] = (short)f2bf(v);
        }
        if (tid < 192) {
            float sc = gamma[tid] * rsqrtf(rv[tid] + 1e-5f);
            bbg[tid] = b[tid] * sc + beta[tid] - rm[tid] * sc;
        }
    } else {
        const int e = (blockIdx.x - 1) * 1024 + tid * 4;
        const int o = e / 192;
        const float sc = gamma[o] * rsqrtf(rv[o] + 1e-5f);
        float4 w = *(const float4*)(W + e);
        short4v s4 = { (short)f2bf(w.x * sc), (short)f2bf(w.y * sc),
                       (short)f2bf(w.z * sc), (short)f2bf(w.w * sc) };
        *(short4v*)(Wpg + e) = s4;
    }
}

// ---------------------------------------------------------------------------
// Kernel C helper: prefetch one timestep's x-fragments for this wave
// (2 c-tiles x 2 k-slices x 4 f32x2 = 32 contiguous-ish bytes per frag).
// ---------------------------------------------------------------------------
#define XLIM (46080000 - 2)
__device__ __forceinline__ void ldx(const float* __restrict__ x, int base,
                                    int wid, int lam, int kc, f32x2 (&xr)[2][2][4]) {
#pragma unroll
    for (int ct = 0; ct < 2; ++ct) {
        const int c = (2 * wid + ct) * 16 + lam;
#pragma unroll
        for (int ks = 0; ks < 2; ++ks)
#pragma unroll
            for (int h = 0; h < 4; ++h) {
                int off = base + c * 15000 + ks * 32 + kc + h * 2;
                off = off < XLIM ? off : XLIM;     // tail clamp (garbage * 0-pad)
                xr[ct][ks][h] = *(const f32x2*)(x + off);
            }
    }
}

// ---------------------------------------------------------------------------
// Kernel C: fused graph-conv + 1x1 conv + BN + ReLU.
// grid (75,32), 192 threads = 3 waves, 4 timesteps/block.
// GEMM1 FLIPPED: D[v][c] = A_scale_pad(64x64) @ x^T; B-frags = 8 contiguous
// floats of x loaded straight to regs (1x redundancy; no LDS staging at all).
// Raw s_barrier + lgkmcnt-only waits: x prefetch for t+1 stays in flight
// across both barriers (no vmcnt(0) drain).  GEMM2 as R8 (flipped, W from
// L2, contiguous stores).  LDS 22 KB; ~5 blocks/CU.
// ---------------------------------------------------------------------------
__global__ __launch_bounds__(192, 3)
void kC(const float* __restrict__ x, const short* __restrict__ Wpg,
        const short* __restrict__ bsTg, const float* __restrict__ bbg,
        float* __restrict__ out) {
    __shared__ __align__(16) short bsT[64 * 72];   // 9216 B
    __shared__ __align__(16) short a2T[32][200];   // 12800 B

    const int tid = threadIdx.x;
    const int lane = tid & 63;
    const int wid = tid >> 6;          // 0..2
    const int lam = lane & 15;
    const int kc = (lane >> 4) * 8;
    const int cb = (lane >> 4) * 4;
    const int n = blockIdx.y;
    const int t0 = blockIdx.x * 4;
    const int base0 = n * 1440000 + t0 * 50;

    // stage A_scale into LDS (576 int4)
    {
        const int4* src = (const int4*)bsTg;
        int4* dst = (int4*)bsT;
        for (int i = tid; i < 576; i += 192) dst[i] = src[i];
    }

    // fused bias resident (o = (4*wid+ot)*16 + lam)
    float bb[4];
#pragma unroll
    for (int ot = 0; ot < 4; ++ot) bb[ot] = bbg[(4 * wid + ot) * 16 + lam];

    // prefetch t0
    f32x2 xr[2][2][4];
    ldx(x, base0, wid, lam, kc, xr);

    asm volatile("s_waitcnt lgkmcnt(0)" ::: "memory");
    __builtin_amdgcn_s_barrier();      // bsT visible; xr loads stay in flight

    const f32x4 z = {0.f, 0.f, 0.f, 0.f};

#pragma unroll 1
    for (int tl = 0; tl < 4; ++tl) {
        // convert prefetched x to bf16 B-fragments
        short8 xb[2][2];
#pragma unroll
        for (int ct = 0; ct < 2; ++ct)
#pragma unroll
            for (int ks = 0; ks < 2; ++ks) {
                union { short4v h[2]; short8 v; } u;
                u.h[0] = cvt4(xr[ct][ks][0].x, xr[ct][ks][0].y, xr[ct][ks][1].x, xr[ct][ks][1].y);
                u.h[1] = cvt4(xr[ct][ks][2].x, xr[ct][ks][2].y, xr[ct][ks][3].x, xr[ct][ks][3].y);
                xb[ct][ks] = u.v;
            }
        if (tl < 3) ldx(x, base0 + (tl + 1) * 50, wid, lam, kc, xr);  // fly over GEMM2

        // ---- GEMM1: D[v][c], A=A_scale_pad rows from LDS, B=xb ----
        f32x4 acc1[2][4];
#pragma unroll
        for (int ct = 0; ct < 2; ++ct)
#pragma unroll
            for (int m = 0; m < 4; ++m) acc1[ct][m] = z;
#pragma unroll
        for (int ks = 0; ks < 2; ++ks)
#pragma unroll
            for (int m = 0; m < 4; ++m) {
                const short8 af = *(const short8*)(bsT + (m * 16 + lam) * 72 + ks * 32 + kc);
#pragma unroll
                for (int ct = 0; ct < 2; ++ct)
                    acc1[ct][m] = __builtin_amdgcn_mfma_f32_16x16x32_bf16(af, xb[ct][ks], acc1[ct][m], 0, 0, 0);
            }

        // scatter agg to a2T[vs][s*96 + c]
#pragma unroll
        for (int ct = 0; ct < 2; ++ct) {
            const int cgl = (2 * wid + ct) * 16 + lam;
#pragma unroll
            for (int m = 0; m < 3; ++m) {           // v = m*16+cb+r <= 47 < 50
                short4v sv = cvt4(acc1[ct][m][0], acc1[ct][m][1], acc1[ct][m][2], acc1[ct][m][3]);
#pragma unroll
                for (int r = 0; r < 4; ++r) {
                    const int v = m * 16 + cb + r;
                    const int s = v >= 25;
                    a2T[v - 25 * s][s * 96 + cgl] = sv[r];
                }
            }
            if (cb == 0) {                          // m=3: only v=48,49 valid
                a2T[23][96 + cgl] = (short)f2bf(acc1[ct][3][0]);
                a2T[24][96 + cgl] = (short)f2bf(acc1[ct][3][1]);
            }
        }

        asm volatile("s_waitcnt lgkmcnt(0)" ::: "memory");
        __builtin_amdgcn_s_barrier();   // a2T ready; xr(t+1) still flying

        // ---- GEMM2: D[tv][o], W'' streamed from L2 ----
        f32x4 acc2[2][4];
#pragma unroll
        for (int mt = 0; mt < 2; ++mt)
#pragma unroll
            for (int ot = 0; ot < 4; ++ot) acc2[mt][ot] = z;
#pragma unroll 2
        for (int ks = 0; ks < 6; ++ks) {
            const short8 A0 = *(const short8*)(&a2T[lam][ks * 32 + kc]);
            const short8 A1 = *(const short8*)(&a2T[16 + lam][ks * 32 + kc]);
#pragma unroll
            for (int ot = 0; ot < 4; ++ot) {
                const short8 w = *(const short8*)(Wpg + ((4 * wid + ot) * 16 + lam) * 192 + ks * 32 + kc);
                acc2[0][ot] = __builtin_amdgcn_mfma_f32_16x16x32_bf16(A0, w, acc2[0][ot], 0, 0, 0);
                acc2[1][ot] = __builtin_amdgcn_mfma_f32_16x16x32_bf16(A1, w, acc2[1][ot], 0, 0, 0);
            }
        }

        // ---- epilogue: ReLU(acc+bias), per-lane contiguous dwords ----
        const int t = t0 + tl;
#pragma unroll
        for (int ot = 0; ot < 4; ++ot) {
            const int o = (4 * wid + ot) * 16 + lam;
            float* op = out + ((size_t)(n * 192 + o) * 300 + t) * 25;
#pragma unroll
            for (int r = 0; r < 4; ++r) {               // tv = cb+r < 16 < 25
                float vv = acc2[0][ot][r] + bb[ot];
                op[cb + r] = vv > 0.f ? vv : 0.f;
            }
#pragma unroll
            for (int r = 0; r < 4; ++r) {               // tv = 16+cb+r
                const int tv = 16 + cb + r;
                if (tv < 25) {
                    float vv = acc2[1][ot][r] + bb[ot];
                    op[tv] = vv > 0.f ? vv : 0.f;
                }
            }
        }

        asm volatile("s_waitcnt lgkmcnt(0)" ::: "memory");
        __builtin_amdgcn_s_barrier();   // a2T WAR before next GEMM1 scatter
    }
}

// ---------------------------------------------------------------------------
extern "C" void kernel_launch(void* const* d_in, const int* in_sizes, int n_in,
                              void* d_out, int out_size, void* d_ws, size_t ws_size,
                              hipStream_t stream) {
    const float* x     = (const float*)d_in[0];
    const float* xx    = (const float*)d_in[1];
    const float* A_res = (const float*)d_in[2];
    const float* W     = (const float*)d_in[3];
    const float* b     = (const float*)d_in[4];
    const float* gamma = (const float*)d_in[5];
    const float* beta  = (const float*)d_in[6];
    const float* rm    = (const float*)d_in[7];
    const float* rv    = (const float*)d_in[8];
    float* out = (float*)d_out;

    char* ws = (char*)d_ws;
    float* At_part  = (float*)ws;                    // 160*625*4 = 400000 B
    float* Acontrib = (float*)(ws + 400000);         // 32*625*4  =  80000 B
    short* bsTg     = (short*)(ws + 480000);         // 64*72*2   =   9216 B
    short* Wpg      = (short*)(ws + 489216);         // 192*192*2 =  73728 B
    float* bbg      = (float*)(ws + 562944);         // 192*4     =    768 B

    kA<<<dim3(5, 32), 256, 0, stream>>>(xx, At_part);
    kB1<<<32, 256, 0, stream>>>(At_part, Acontrib);
    kB2<<<37, 256, 0, stream>>>(Acontrib, A_res, W, b, gamma, beta, rm, rv, bsTg, Wpg, bbg);
    kC<<<dim3(75, 32), 192, 0, stream>>>(x, Wpg, bsTg, bbg, out);
}

// Round 10
// 187.518 us; speedup vs baseline: 1.2608x; 1.2608x over previous
//
#include <hip/hip_runtime.h>
#include <hip/hip_bf16.h>

typedef __attribute__((ext_vector_type(8))) short short8;
typedef __attribute__((ext_vector_type(4))) short short4v;
typedef __attribute__((ext_vector_type(4))) float f32x4;
typedef __attribute__((ext_vector_type(2))) float f32x2;

__device__ __forceinline__ unsigned short f2bf(float f) {
    unsigned int u = __builtin_bit_cast(unsigned int, f);
    u += 0x7fffu + ((u >> 16) & 1u);   // round-to-nearest-even
    return (unsigned short)(u >> 16);
}
__device__ __forceinline__ short4v cvt4(float a, float b, float c, float d) {
    union { __hip_bfloat162 h[2]; short4v s; } u;
    u.h[0] = __float22bfloat162_rn(make_float2(a, b));
    u.h[1] = __float22bfloat162_rn(make_float2(c, d));
    return u.s;
}

// ---------------------------------------------------------------------------
// Kernel A: partial adjacency sums over 60-frame chunks. grid (5,32).
// ---------------------------------------------------------------------------
__global__ void kA(const float* __restrict__ xx, float* __restrict__ At_part) {
    __shared__ float xs3[3][60][25];
    const int tc = blockIdx.x, n = blockIdx.y;
    const int tid = threadIdx.x;
    const float* base = xx + (size_t)n * 22500 + tc * 1500;
    for (int idx = tid; idx < 4500; idx += 256) {
        int ch = idx / 1500, rt = idx % 1500;
        xs3[ch][rt / 25][rt % 25] = base[ch * 7500 + rt];
    }
    __syncthreads();
    for (int p = tid; p < 625; p += 256) {
        int v = p / 25, u = p % 25;
        float s = 0.f;
        for (int t = 0; t < 60; ++t) {
            float dx = xs3[0][t][v] - xs3[0][t][u];
            float dy = xs3[1][t][v] - xs3[1][t][u];
            float dz = xs3[2][t][v] - xs3[2][t][u];
            s += __expf(-2.f * (dx * dx + dy * dy + dz * dz));
        }
        At_part[(size_t)(n * 5 + tc) * 625 + p] = s;
    }
}

// ---------------------------------------------------------------------------
// Kernel B1: per-sample reduce + symmetric normalization. grid 32.
// ---------------------------------------------------------------------------
__global__ void kB1(const float* __restrict__ At_part, float* __restrict__ Acontrib) {
    __shared__ float At[625];
    __shared__ float dinv[25];
    const int n = blockIdx.x, tid = threadIdx.x;
    for (int p = tid; p < 625; p += 256) {
        float s = 0.f;
        for (int tc = 0; tc < 5; ++tc) s += At_part[(size_t)(n * 5 + tc) * 625 + p];
        At[p] = s;
    }
    __syncthreads();
    if (tid < 25) {
        float d = 0.f;
        for (int u = 0; u < 25; ++u) d += At[tid * 25 + u];
        dinv[tid] = rsqrtf(d * (1.f / 300.f));
    }
    __syncthreads();
    for (int p = tid; p < 625; p += 256)
        Acontrib[n * 625 + p] = At[p] * (1.f / 300.f) * dinv[p / 25] * dinv[p % 25] * (1.f / 32.f);
}

// ---------------------------------------------------------------------------
// Kernel B2: block 0 -> bsTg (bf16 [64][72], zero-padded) + fused bias;
//            blocks 1..36 -> W'' = W * bn_scale  (layout [o][k], row-major).
// ---------------------------------------------------------------------------
__global__ void kB2(const float* __restrict__ Acontrib, const float* __restrict__ A_res,
                    const float* __restrict__ W, const float* __restrict__ b,
                    const float* __restrict__ gamma, const float* __restrict__ beta,
                    const float* __restrict__ rm, const float* __restrict__ rv,
                    short* __restrict__ bsTg, short* __restrict__ Wpg,
                    float* __restrict__ bbg) {
    const int tid = threadIdx.x;
    if (blockIdx.x == 0) {
        __shared__ float macc[625];
        for (int p = tid; p < 625; p += 256) {
            float s = 0.f;
            for (int n = 0; n < 32; ++n) s += Acontrib[n * 625 + p];
            macc[p] = s;
        }
        __syncthreads();
        for (int idx = tid; idx < 64 * 72; idx += 256) {
            int col = idx / 72, u = idx % 72;
            float v = 0.f;
            if (col < 50 && u < 50) v = macc[(col % 25) * 25 + (u % 25)] + A_res[col * 50 + u];
            bsTg[idx] = (short)f2bf(v);
        }
        if (tid < 192) {
            float sc = gamma[tid] * rsqrtf(rv[tid] + 1e-5f);
            bbg[tid] = b[tid] * sc + beta[tid] - rm[tid] * sc;
        }
    } else {
        const int e = (blockIdx.x - 1) * 1024 + tid * 4;
        const int o = e / 192;
        const float sc = gamma[o] * rsqrtf(rv[o] + 1e-5f);
        float4 w = *(const float4*)(W + e);
        short4v s4 = { (short)f2bf(w.x * sc), (short)f2bf(w.y * sc),
                       (short)f2bf(w.z * sc), (short)f2bf(w.w * sc) };
        *(short4v*)(Wpg + e) = s4;
    }
}

// ---------------------------------------------------------------------------
// Kernel C helper: prefetch this wave's x-fragments for one timestep.
// 8 x f32x2 (8B, always 8B-aligned: all index terms even).
// ---------------------------------------------------------------------------
#define XLIM (46080000 - 2)
__device__ __forceinline__ void ldx(const float* __restrict__ x, int rowbase,
                                    int kc, f32x2 (&xr)[2][4]) {
#pragma unroll
    for (int ks = 0; ks < 2; ++ks)
#pragma unroll
        for (int h = 0; h < 4; ++h) {
            int off = rowbase + ks * 32 + kc + h * 2;
            off = off < XLIM ? off : XLIM;     // tail clamp (garbage * 0-pad)
            xr[ks][h] = *(const f32x2*)(x + off);
        }
}

// ---------------------------------------------------------------------------
// Kernel C: fused graph-conv + 1x1 conv + BN + ReLU.
// grid (75,32), 384 threads = 6 waves, 4 timesteps/block.
// In the steady loop the ONLY vmem are x prefetch loads + out stores:
// W'' lives in registers (wf[2][6], loaded once pre-loop) -> no in-loop
// vmem wait can force the x prefetch to drain (vmcnt retires IN ORDER;
// R8/R9's L2-streamed W did exactly that and serialized every iteration).
// a2T double-buffered -> ONE barrier per iteration.
// GEMM1 flipped: D[v][c], x loaded reg-direct (no staging).
// GEMM2 flipped: D[tv][o] -> contiguous stores.
// LDS 34.8 KB; ~130 VGPR at (384,3) -> 2 blocks/CU, no spill.
// ---------------------------------------------------------------------------
__global__ __launch_bounds__(384, 3)
void kC(const float* __restrict__ x, const short* __restrict__ Wpg,
        const short* __restrict__ bsTg, const float* __restrict__ bbg,
        float* __restrict__ out) {
    __shared__ __align__(16) short bsT[64 * 72];        // 9216 B
    __shared__ __align__(16) short a2T[2][32][200];     // 25600 B

    const int tid = threadIdx.x;
    const int lane = tid & 63;
    const int wid = tid >> 6;          // 0..5
    const int lam = lane & 15;
    const int kc = (lane >> 4) * 8;
    const int cb = (lane >> 4) * 4;
    const int n = blockIdx.y;
    const int t0 = blockIdx.x * 4;
    // this wave's GEMM1 x-row: c = wid*16 + lam
    const int rowb0 = n * 1440000 + (wid * 16 + lam) * 15000 + t0 * 50;

    // prefetch t0 first (longest latency)
    f32x2 xr[2][4];
    ldx(x, rowb0, kc, xr);

    // W'' fragments resident: wave owns o-tiles (2*wid+ot)*16, ot=0,1
    short8 wf[2][6];
#pragma unroll
    for (int ot = 0; ot < 2; ++ot)
#pragma unroll
        for (int ks = 0; ks < 6; ++ks)
            wf[ot][ks] = *(const short8*)(Wpg + ((2 * wid + ot) * 16 + lam) * 192 + ks * 32 + kc);

    // fused bias
    float bb[2];
#pragma unroll
    for (int ot = 0; ot < 2; ++ot) bb[ot] = bbg[(2 * wid + ot) * 16 + lam];

    // stage A_scale into LDS (576 int4)
    {
        const int4* src = (const int4*)bsTg;
        int4* dst = (int4*)bsT;
        for (int i = tid; i < 576; i += 384) dst[i] = src[i];
    }

    asm volatile("s_waitcnt lgkmcnt(0)" ::: "memory");
    __builtin_amdgcn_s_barrier();      // bsT visible; x loads stay in flight

    const f32x4 z = {0.f, 0.f, 0.f, 0.f};
    const int cgl = wid * 16 + lam;

#pragma unroll 1
    for (int tl = 0; tl < 4; ++tl) {
        short* a2w = &a2T[tl & 1][0][0];

        // convert prefetched x -> bf16 B-fragments (waits on x loads only;
        // out stores issued after them don't block this wait)
        short8 xb[2];
#pragma unroll
        for (int ks = 0; ks < 2; ++ks) {
            union { short4v h[2]; short8 v; } u;
            u.h[0] = cvt4(xr[ks][0].x, xr[ks][0].y, xr[ks][1].x, xr[ks][1].y);
            u.h[1] = cvt4(xr[ks][2].x, xr[ks][2].y, xr[ks][3].x, xr[ks][3].y);
            xb[ks] = u.v;
        }
        if (tl < 3) ldx(x, rowb0 + (tl + 1) * 50, kc, xr);   // spans whole iter

        // ---- GEMM1: D[v][c] = A_scale_pad @ x^T (8 MFMA) ----
        f32x4 acc1[4];
#pragma unroll
        for (int m = 0; m < 4; ++m) acc1[m] = z;
#pragma unroll
        for (int ks = 0; ks < 2; ++ks)
#pragma unroll
            for (int m = 0; m < 4; ++m) {
                const short8 af = *(const short8*)(bsT + (m * 16 + lam) * 72 + ks * 32 + kc);
                acc1[m] = __builtin_amdgcn_mfma_f32_16x16x32_bf16(af, xb[ks], acc1[m], 0, 0, 0);
            }

        // scatter agg -> a2T[tl&1][vs][s*96 + c]
#pragma unroll
        for (int m = 0; m < 3; ++m) {               // v = m*16+cb+r <= 47
            short4v sv = cvt4(acc1[m][0], acc1[m][1], acc1[m][2], acc1[m][3]);
#pragma unroll
            for (int r = 0; r < 4; ++r) {
                const int v = m * 16 + cb + r;
                const int s = v >= 25;
                a2w[(v - 25 * s) * 200 + s * 96 + cgl] = sv[r];
            }
        }
        if (cb == 0) {                              // m=3: only v=48,49 valid
            a2w[23 * 200 + 96 + cgl] = (short)f2bf(acc1[3][0]);
            a2w[24 * 200 + 96 + cgl] = (short)f2bf(acc1[3][1]);
        }

        asm volatile("s_waitcnt lgkmcnt(0)" ::: "memory");
        __builtin_amdgcn_s_barrier();   // a2T[tl&1] ready; xr(t+1) still flying

        // ---- GEMM2: D[tv][o], W'' from registers (24 MFMA) ----
        f32x4 acc2[2][2];
#pragma unroll
        for (int g = 0; g < 2; ++g) { acc2[g][0] = z; acc2[g][1] = z; }
#pragma unroll
        for (int ks = 0; ks < 6; ++ks) {
            const short8 A0 = *(const short8*)(a2w + lam * 200 + ks * 32 + kc);
            const short8 A1 = *(const short8*)(a2w + (16 + lam) * 200 + ks * 32 + kc);
#pragma unroll
            for (int ot = 0; ot < 2; ++ot) {
                acc2[0][ot] = __builtin_amdgcn_mfma_f32_16x16x32_bf16(A0, wf[ot][ks], acc2[0][ot], 0, 0, 0);
                acc2[1][ot] = __builtin_amdgcn_mfma_f32_16x16x32_bf16(A1, wf[ot][ks], acc2[1][ot], 0, 0, 0);
            }
        }

        // ---- epilogue: ReLU(acc+bias), contiguous per-lane dwords ----
        const int t = t0 + tl;
#pragma unroll
        for (int ot = 0; ot < 2; ++ot) {
            const int o = (2 * wid + ot) * 16 + lam;
            float* op = out + ((size_t)(n * 192 + o) * 300 + t) * 25;
#pragma unroll
            for (int r = 0; r < 4; ++r) {           // tv = cb+r < 16
                float vv = acc2[0][ot][r] + bb[ot];
                op[cb + r] = vv > 0.f ? vv : 0.f;
            }
#pragma unroll
            for (int r = 0; r < 4; ++r) {           // tv = 16+cb+r
                const int tv = 16 + cb + r;
                if (tv < 25) {
                    float vv = acc2[1][ot][r] + bb[ot];
                    op[tv] = vv > 0.f ? vv : 0.f;
                }
            }
        }
        // no trailing barrier: next iter scatters into the OTHER a2T buffer;
        // barrier(tl+1) orders it after all GEMM2(tl) reads.
    }
}

// ---------------------------------------------------------------------------
extern "C" void kernel_launch(void* const* d_in, const int* in_sizes, int n_in,
                              void* d_out, int out_size, void* d_ws, size_t ws_size,
                              hipStream_t stream) {
    const float* x     = (const float*)d_in[0];
    const float* xx    = (const float*)d_in[1];
    const float* A_res = (const float*)d_in[2];
    const float* W     = (const float*)d_in[3];
    const float* b     = (const float*)d_in[4];
    const float* gamma = (const float*)d_in[5];
    const float* beta  = (const float*)d_in[6];
    const float* rm    = (const float*)d_in[7];
    const float* rv    = (const float*)d_in[8];
    float* out = (float*)d_out;

    char* ws = (char*)d_ws;
    float* At_part  = (float*)ws;                    // 160*625*4 = 400000 B
    float* Acontrib = (float*)(ws + 400000);         // 32*625*4  =  80000 B
    short* bsTg     = (short*)(ws + 480000);         // 64*72*2   =   9216 B
    short* Wpg      = (short*)(ws + 489216);         // 192*192*2 =  73728 B
    float* bbg      = (float*)(ws + 562944);         // 192*4     =    768 B

    kA<<<dim3(5, 32), 256, 0, stream>>>(xx, At_part);
    kB1<<<32, 256, 0, stream>>>(At_part, Acontrib);
    kB2<<<37, 256, 0, stream>>>(Acontrib, A_res, W, b, gamma, beta, rm, rv, bsTg, Wpg, bbg);
    kC<<<dim3(75, 32), 384, 0, stream>>>(x, Wpg, bsTg, bbg, out);
}

// Round 11
// 181.496 us; speedup vs baseline: 1.3026x; 1.0332x over previous
//
#include <hip/hip_runtime.h>
#include <hip/hip_bf16.h>

typedef __attribute__((ext_vector_type(8))) short short8;
typedef __attribute__((ext_vector_type(4))) short short4v;
typedef __attribute__((ext_vector_type(4))) float f32x4;
typedef __attribute__((ext_vector_type(2))) float f32x2;

__device__ __forceinline__ unsigned short f2bf(float f) {
    unsigned int u = __builtin_bit_cast(unsigned int, f);
    u += 0x7fffu + ((u >> 16) & 1u);   // round-to-nearest-even
    return (unsigned short)(u >> 16);
}
__device__ __forceinline__ unsigned int pack2(float a, float b) {
    union { __hip_bfloat162 h; unsigned int u; } r;
    r.h = __float22bfloat162_rn(make_float2(a, b));
    return r.u;
}
__device__ __forceinline__ short4v cvt4(float a, float b, float c, float d) {
    union { __hip_bfloat162 h[2]; short4v s; } u;
    u.h[0] = __float22bfloat162_rn(make_float2(a, b));
    u.h[1] = __float22bfloat162_rn(make_float2(c, d));
    return u.s;
}

// ---------------------------------------------------------------------------
// Kernel A: partial adjacency sums over 60-frame chunks. grid (5,32).
// ---------------------------------------------------------------------------
__global__ void kA(const float* __restrict__ xx, float* __restrict__ At_part) {
    __shared__ float xs3[3][60][25];
    const int tc = blockIdx.x, n = blockIdx.y;
    const int tid = threadIdx.x;
    const float* base = xx + (size_t)n * 22500 + tc * 1500;
    for (int idx = tid; idx < 4500; idx += 256) {
        int ch = idx / 1500, rt = idx % 1500;
        xs3[ch][rt / 25][rt % 25] = base[ch * 7500 + rt];
    }
    __syncthreads();
    for (int p = tid; p < 625; p += 256) {
        int v = p / 25, u = p % 25;
        float s = 0.f;
        for (int t = 0; t < 60; ++t) {
            float dx = xs3[0][t][v] - xs3[0][t][u];
            float dy = xs3[1][t][v] - xs3[1][t][u];
            float dz = xs3[2][t][v] - xs3[2][t][u];
            s += __expf(-2.f * (dx * dx + dy * dy + dz * dz));
        }
        At_part[(size_t)(n * 5 + tc) * 625 + p] = s;
    }
}

// ---------------------------------------------------------------------------
// Kernel B1: per-sample reduce + symmetric normalization. grid 32.
// ---------------------------------------------------------------------------
__global__ void kB1(const float* __restrict__ At_part, float* __restrict__ Acontrib) {
    __shared__ float At[625];
    __shared__ float dinv[25];
    const int n = blockIdx.x, tid = threadIdx.x;
    for (int p = tid; p < 625; p += 256) {
        float s = 0.f;
        for (int tc = 0; tc < 5; ++tc) s += At_part[(size_t)(n * 5 + tc) * 625 + p];
        At[p] = s;
    }
    __syncthreads();
    if (tid < 25) {
        float d = 0.f;
        for (int u = 0; u < 25; ++u) d += At[tid * 25 + u];
        dinv[tid] = rsqrtf(d * (1.f / 300.f));
    }
    __syncthreads();
    for (int p = tid; p < 625; p += 256)
        Acontrib[n * 625 + p] = At[p] * (1.f / 300.f) * dinv[p / 25] * dinv[p % 25] * (1.f / 32.f);
}

// ---------------------------------------------------------------------------
// Kernel B2: block 0 -> bsTg (bf16 [64][72], zero-padded) + fused bias;
//            blocks 1..36 -> W'' = W * bn_scale  (layout [o][k], row-major).
// ---------------------------------------------------------------------------
__global__ void kB2(const float* __restrict__ Acontrib, const float* __restrict__ A_res,
                    const float* __restrict__ W, const float* __restrict__ b,
                    const float* __restrict__ gamma, const float* __restrict__ beta,
                    const float* __restrict__ rm, const float* __restrict__ rv,
                    short* __restrict__ bsTg, short* __restrict__ Wpg,
                    float* __restrict__ bbg) {
    const int tid = threadIdx.x;
    if (blockIdx.x == 0) {
        __shared__ float macc[625];
        for (int p = tid; p < 625; p += 256) {
            float s = 0.f;
            for (int n = 0; n < 32; ++n) s += Acontrib[n * 625 + p];
            macc[p] = s;
        }
        __syncthreads();
        for (int idx = tid; idx < 64 * 72; idx += 256) {
            int col = idx / 72, u = idx % 72;
            float v = 0.f;
            if (col < 50 && u < 50) v = macc[(col % 25) * 25 + (u % 25)] + A_res[col * 50 + u];
            bsTg[idx] = (short)f2bf(v);
        }
        if (tid < 192) {
            float sc = gamma[tid] * rsqrtf(rv[tid] + 1e-5f);
            bbg[tid] = b[tid] * sc + beta[tid] - rm[tid] * sc;
        }
    } else {
        const int e = (blockIdx.x - 1) * 1024 + tid * 4;
        const int o = e / 192;
        const float sc = gamma[o] * rsqrtf(rv[o] + 1e-5f);
        float4 w = *(const float4*)(W + e);
        short4v s4 = { (short)f2bf(w.x * sc), (short)f2bf(w.y * sc),
                       (short)f2bf(w.z * sc), (short)f2bf(w.w * sc) };
        *(short4v*)(Wpg + e) = s4;
    }
}

// ---------------------------------------------------------------------------
// Kernel C helpers: COALESCED per-t staging. One t = 96 rows x 25 f32x2;
// lane-consecutive idx -> contiguous addresses within each x row.
// ---------------------------------------------------------------------------
__device__ __forceinline__ void ldx(const float* __restrict__ x, int gbase,
                                    f32x2 (&pf)[7], int tid) {
#pragma unroll
    for (int i = 0; i < 7; ++i) {
        int idx = i * 384 + tid;
        idx = idx < 2400 ? idx : 2399;
        int c = idx / 25, q = idx - c * 25;
        pf[i] = *(const f32x2*)(x + gbase + c * 15000 + 2 * q);
    }
}
__device__ __forceinline__ void stx(char* xsb, int slot, const f32x2 (&pf)[7], int tid) {
#pragma unroll
    for (int i = 0; i < 7; ++i) {
        int idx = i * 384 + tid;
        if (idx < 2400) {
            int c = idx / 25, q = idx - c * 25;
            *(unsigned int*)(xsb + ((slot * 12288 + c * 128 + q * 4) ^ ((c & 7) << 4)))
                = pack2(pf[i].x, pf[i].y);
        }
    }
}

// ---------------------------------------------------------------------------
// Kernel C: fused graph-conv + 1x1 conv + BN + ReLU.
// grid (75,32), 384 threads = 6 waves, 4 timesteps/block.
// - x staged COALESCED into 2-slot LDS (scattered per-lane-row reads move to
//   LDS, which is banked + swizzled; the R10 TA-transaction flood is gone).
// - W'' resident in regs (wf[2][6]=48 VGPR/wave); only x loads + out stores
//   in the loop's VMEM stream -> prefetch never drained (in-order vmcnt).
// - a2T double-buffered, 208-short rows -> ONE barrier per timestep.
// LDS 60.4 KB; (384,3) -> 170-reg budget, demand ~130 -> no spill, 2 blk/CU.
// ---------------------------------------------------------------------------
__global__ __launch_bounds__(384, 3)
void kC(const float* __restrict__ x, const short* __restrict__ Wpg,
        const short* __restrict__ bsTg, const float* __restrict__ bbg,
        float* __restrict__ out) {
    __shared__ __align__(16) char xsb[2 * 12288];       // 24576 B, 2 t-slots
    __shared__ __align__(16) short bsT[64 * 72];        // 9216 B
    __shared__ __align__(16) short a2T[2][32][208];     // 26624 B

    const int tid = threadIdx.x;
    const int lane = tid & 63;
    const int wid = tid >> 6;          // 0..5
    const int lam = lane & 15;
    const int kc = (lane >> 4) * 8;
    const int cb = (lane >> 4) * 4;
    const int n = blockIdx.y;
    const int t0 = blockIdx.x * 4;
    const int gb0 = n * 1440000 + t0 * 50;
    const int cgl = wid * 16 + lam;    // this wave's GEMM1 c-column

    // ---- prologue ----
    // dual-t coalesced load (t0,t1): 4800 f32x2
    f32x2 pf2[13];
#pragma unroll
    for (int i = 0; i < 13; ++i) {
        int idx = i * 384 + tid;
        idx = idx < 4800 ? idx : 4799;
        int c = idx / 50, q2 = idx - c * 50;
        int tl = q2 >= 25, q = q2 - 25 * tl;
        pf2[i] = *(const f32x2*)(x + gb0 + c * 15000 + tl * 50 + 2 * q);
    }

    // W'' fragments resident: wave owns o-tiles (2*wid+ot)*16
    short8 wf[2][6];
#pragma unroll
    for (int ot = 0; ot < 2; ++ot)
#pragma unroll
        for (int ks = 0; ks < 6; ++ks)
            wf[ot][ks] = *(const short8*)(Wpg + ((2 * wid + ot) * 16 + lam) * 192 + ks * 32 + kc);

    float bb[2];
#pragma unroll
    for (int ot = 0; ot < 2; ++ot) bb[ot] = bbg[(2 * wid + ot) * 16 + lam];

    // stage A_scale (576 int4)
    {
        const int4* src = (const int4*)bsTg;
        int4* dst = (int4*)bsT;
        for (int i = tid; i < 576; i += 384) dst[i] = src[i];
    }
    // zero xs pads u=50..63 (both slots): 96*7*2 dwords
    for (int idx = tid; idx < 1344; idx += 384) {
        int r = idx / 7, k = idx - r * 7;
        int slot = r / 96, c = r - 96 * slot;
        *(unsigned int*)(xsb + ((slot * 12288 + c * 128 + (50 + 2 * k) * 2) ^ ((c & 7) << 4))) = 0;
    }
    // zero a2T pad rows 25..31 (both buffers): 2*7*104 dwords
    for (int idx = tid; idx < 1456; idx += 384) {
        int buf = idx / 728, rem = idx - buf * 728;
        int row = 25 + rem / 104, col2 = rem - (rem / 104) * 104;
        *((unsigned int*)&a2T[buf][row][0] + col2) = 0;
    }
    // write t0 -> slot0, t1 -> slot1 (waits pf2 loads only)
#pragma unroll
    for (int i = 0; i < 13; ++i) {
        int idx = i * 384 + tid;
        if (idx < 4800) {
            int c = idx / 50, q2 = idx - c * 50;
            int tl = q2 >= 25, q = q2 - 25 * tl;
            *(unsigned int*)(xsb + ((tl * 12288 + c * 128 + q * 4) ^ ((c & 7) << 4)))
                = pack2(pf2[i].x, pf2[i].y);
        }
    }
    asm volatile("s_waitcnt lgkmcnt(0)" ::: "memory");
    __builtin_amdgcn_s_barrier();

    const f32x4 z = {0.f, 0.f, 0.f, 0.f};
    f32x2 pf[7];

#pragma unroll 1
    for (int tl = 0; tl < 4; ++tl) {
        const int slot = tl & 1;
        short* a2w = &a2T[slot][0][0];

        // issue t+2 coalesced loads early (consumed by stx after GEMM2)
        if (tl < 2) ldx(x, gb0 + (tl + 2) * 50, pf, tid);

        // ---- GEMM1: D[v][c] = A_scale_pad @ x^T (8 MFMA) ----
        short8 xb[2];
#pragma unroll
        for (int ks = 0; ks < 2; ++ks)
            xb[ks] = *(const short8*)(xsb +
                ((slot * 12288 + cgl * 128 + (ks * 32 + kc) * 2) ^ ((cgl & 7) << 4)));
        f32x4 acc1[4];
#pragma unroll
        for (int m = 0; m < 4; ++m) acc1[m] = z;
#pragma unroll
        for (int ks = 0; ks < 2; ++ks)
#pragma unroll
            for (int m = 0; m < 4; ++m) {
                const short8 af = *(const short8*)(bsT + (m * 16 + lam) * 72 + ks * 32 + kc);
                acc1[m] = __builtin_amdgcn_mfma_f32_16x16x32_bf16(af, xb[ks], acc1[m], 0, 0, 0);
            }

        // scatter agg -> a2T[slot][vs][s*96 + c]
#pragma unroll
        for (int m = 0; m < 3; ++m) {               // v = m*16+cb+r <= 47
            short4v sv = cvt4(acc1[m][0], acc1[m][1], acc1[m][2], acc1[m][3]);
#pragma unroll
            for (int r = 0; r < 4; ++r) {
                const int v = m * 16 + cb + r;
                const int s = v >= 25;
                a2w[(v - 25 * s) * 208 + s * 96 + cgl] = sv[r];
            }
        }
        if (cb == 0) {                              // m=3: only v=48,49 valid
            a2w[23 * 208 + 96 + cgl] = (short)f2bf(acc1[3][0]);
            a2w[24 * 208 + 96 + cgl] = (short)f2bf(acc1[3][1]);
        }

        asm volatile("s_waitcnt lgkmcnt(0)" ::: "memory");
        __builtin_amdgcn_s_barrier();   // a2T[slot] ready; xs[slot] reads done

        // ---- GEMM2: D[tv][o], W'' from registers (24 MFMA) ----
        f32x4 acc2[2][2];
#pragma unroll
        for (int g = 0; g < 2; ++g) { acc2[g][0] = z; acc2[g][1] = z; }
#pragma unroll
        for (int ks = 0; ks < 6; ++ks) {
            const short8 A0 = *(const short8*)(a2w + lam * 208 + ks * 32 + kc);
            const short8 A1 = *(const short8*)(a2w + (16 + lam) * 208 + ks * 32 + kc);
#pragma unroll
            for (int ot = 0; ot < 2; ++ot) {
                acc2[0][ot] = __builtin_amdgcn_mfma_f32_16x16x32_bf16(A0, wf[ot][ks], acc2[0][ot], 0, 0, 0);
                acc2[1][ot] = __builtin_amdgcn_mfma_f32_16x16x32_bf16(A1, wf[ot][ks], acc2[1][ot], 0, 0, 0);
            }
        }

        // write t+2 into the just-freed slot (all waves passed the barrier)
        if (tl < 2) stx(xsb, slot, pf, tid);

        // ---- epilogue: ReLU(acc+bias), contiguous per-lane dwords ----
        const int t = t0 + tl;
#pragma unroll
        for (int ot = 0; ot < 2; ++ot) {
            const int o = (2 * wid + ot) * 16 + lam;
            float* op = out + ((size_t)(n * 192 + o) * 300 + t) * 25;
#pragma unroll
            for (int r = 0; r < 4; ++r) {           // tv = cb+r < 16
                float vv = acc2[0][ot][r] + bb[ot];
                op[cb + r] = vv > 0.f ? vv : 0.f;
            }
#pragma unroll
            for (int r = 0; r < 4; ++r) {           // tv = 16+cb+r
                const int tv = 16 + cb + r;
                if (tv < 25) {
                    float vv = acc2[1][ot][r] + bb[ot];
                    op[tv] = vv > 0.f ? vv : 0.f;
                }
            }
        }
        // no trailing barrier: next iteration uses the OTHER xs slot / a2T
        // buffer; its barrier (after lgkmcnt(0)) orders this iteration's
        // stx writes before the t+2 reads.
    }
}

// ---------------------------------------------------------------------------
extern "C" void kernel_launch(void* const* d_in, const int* in_sizes, int n_in,
                              void* d_out, int out_size, void* d_ws, size_t ws_size,
                              hipStream_t stream) {
    const float* x     = (const float*)d_in[0];
    const float* xx    = (const float*)d_in[1];
    const float* A_res = (const float*)d_in[2];
    const float* W     = (const float*)d_in[3];
    const float* b     = (const float*)d_in[4];
    const float* gamma = (const float*)d_in[5];
    const float* beta  = (const float*)d_in[6];
    const float* rm    = (const float*)d_in[7];
    const float* rv    = (const float*)d_in[8];
    float* out = (float*)d_out;

    char* ws = (char*)d_ws;
    float* At_part  = (float*)ws;                    // 160*625*4 = 400000 B
    float* Acontrib = (float*)(ws + 400000);         // 32*625*4  =  80000 B
    short* bsTg     = (short*)(ws + 480000);         // 64*72*2   =   9216 B
    short* Wpg      = (short*)(ws + 489216);         // 192*192*2 =  73728 B
    float* bbg      = (float*)(ws + 562944);         // 192*4     =    768 B

    kA<<<dim3(5, 32), 256, 0, stream>>>(xx, At_part);
    kB1<<<32, 256, 0, stream>>>(At_part, Acontrib);
    kB2<<<37, 256, 0, stream>>>(Acontrib, A_res, W, b, gamma, beta, rm, rv, bsTg, Wpg, bbg);
    kC<<<dim3(75, 32), 384, 0, stream>>>(x, Wpg, bsTg, bbg, out);
}